// Round 1
// baseline (789.262 us; speedup 1.0000x reference)
//
#include <hip/hip_runtime.h>
#include <math.h>

// Problem constants (match reference):
#define BB    2
#define NN    8192
#define DD    256
#define NBINS 32
#define BINSZ 256
#define NPROJ 16     // n_bins // 2
#define TOPK  16
#define NPTS  (BB * NN)   // 16384

// ---------------------------------------------------------------------------
// K1: bin assignment. One thread per point; codebook (first 16 cols) in LDS.
// fp64 accumulation to minimize divergence from the CPU fp32 reference.
// ---------------------------------------------------------------------------
__global__ __launch_bounds__(64) void k_bins(const float* __restrict__ x,
                                             const float* __restrict__ cb,
                                             int* __restrict__ bin_idx) {
    __shared__ float cbt[DD][NPROJ];   // 16 KB
    const int t = threadIdx.x;         // 0..63
    for (int q = t; q < DD * NPROJ; q += 64) {
        int d = q >> 4, j = q & 15;
        cbt[d][j] = cb[d * 32 + j];    // codebook is (256, 32); use cols 0..15
    }
    __syncthreads();

    const int p = blockIdx.x * 64 + t;            // 0..16383 (flat over B,N)
    const float* xr = x + (size_t)p * DD;

    double a[NPROJ];
#pragma unroll
    for (int j = 0; j < NPROJ; ++j) a[j] = 0.0;

    for (int d0 = 0; d0 < DD; d0 += 4) {
        float4 xv = *(const float4*)(xr + d0);
        float xs[4] = {xv.x, xv.y, xv.z, xv.w};
#pragma unroll
        for (int dd = 0; dd < 4; ++dd) {
            double xd = (double)xs[dd];
#pragma unroll
            for (int j = 0; j < NPROJ; ++j)
                a[j] = fma((double)cbt[d0 + dd][j], xd, a[j]);
        }
    }

    // argmax over cmul = [m0..m15, -m0..-m15], first occurrence of max.
    float bv = -INFINITY; int bj = 0;
#pragma unroll
    for (int j = 0; j < NPROJ; ++j) {
        float m = (float)a[j];
        if (m > bv) { bv = m; bj = j; }
    }
#pragma unroll
    for (int j = 0; j < NPROJ; ++j) {
        float m = -(float)a[j];
        if (m > bv) { bv = m; bj = j + NPROJ; }
    }
    bin_idx[p] = bj;
}

// ---------------------------------------------------------------------------
// K2: stable counting sort (== stable argsort of bin ids). One block per batch.
// 256 threads x 32 contiguous points each; counts in LDS c[bin][thread];
// bin-major prefix over (bin, thread) gives the stable global position.
// ---------------------------------------------------------------------------
__global__ __launch_bounds__(256) void k_sort(const int* __restrict__ bin_idx,
                                              int* __restrict__ order) {
    __shared__ int c[NBINS][256];   // 32 KB
    __shared__ int base[NBINS];
    const int t = threadIdx.x;
    const int b = blockIdx.x;
    const int* bi = bin_idx + b * NN;

    for (int j = 0; j < NBINS; ++j) c[j][t] = 0;
    __syncthreads();

    const int i0 = t * 32;
    for (int i = 0; i < 32; ++i) c[bi[i0 + i]][t]++;
    __syncthreads();

    if (t < NBINS) {                 // per-bin totals
        int s = 0;
        for (int q = 0; q < 256; ++q) s += c[t][q];
        base[t] = s;
    }
    __syncthreads();
    if (t == 0) {                    // exclusive prefix over bins
        int run = 0;
        for (int j = 0; j < NBINS; ++j) { int tmp = base[j]; base[j] = run; run += tmp; }
    }
    __syncthreads();
    if (t < NBINS) {                 // exclusive prefix over threads within bin
        int run = base[t];
        for (int q = 0; q < 256; ++q) { int tmp = c[t][q]; c[t][q] = run; run += tmp; }
    }
    __syncthreads();

    int* ob = order + b * NN;
    for (int i = 0; i < 32; ++i) {
        int gi = i0 + i;
        int bb = bi[gi];
        int pos = c[bb][t]++;        // column t is thread-exclusive
        ob[pos] = gi;
    }
}

// ---------------------------------------------------------------------------
// K3: per (batch, bin, 32-row tile): S = P P^T rows in fp64, sigmoid to fp32,
// exact top-16 (desc value, ties -> lowest index), scatter into out.
// Block = 256 threads (one per column). grid = 2*32*8 = 512.
// ---------------------------------------------------------------------------
#define RT 32
__global__ __launch_bounds__(256) void k_sim(const float* __restrict__ x,
                                             const int* __restrict__ order,
                                             float* __restrict__ out) {
    __shared__ int    idx[BINSZ];            // 1 KB
    __shared__ double Ad[RT][33];            // 8.25 KB (pad -> conflict-free)
    __shared__ float  S[RT][BINSZ + 1];      // ~33 KB

    const int t   = threadIdx.x;
    const int bid = blockIdx.x;              // 0..511
    const int b   = bid >> 8;
    const int bin = (bid >> 3) & 31;
    const int r0  = (bid & 7) * RT;

    idx[t] = order[b * NN + bin * BINSZ + t];
    __syncthreads();

    const float* xb = x + (size_t)b * NN * DD;
    const float* xc = xb + (size_t)idx[t] * DD;   // my column's point row

    double acc[RT];
#pragma unroll
    for (int r = 0; r < RT; ++r) acc[r] = 0.0;

#pragma unroll 1
    for (int k0 = 0; k0 < DD; k0 += 32) {
        // my column's 32-float chunk (one 128B line per lane)
        float bcol[32];
#pragma unroll
        for (int q = 0; q < 8; ++q) {
            float4 v = *(const float4*)(xc + k0 + q * 4);
            bcol[q * 4 + 0] = v.x; bcol[q * 4 + 1] = v.y;
            bcol[q * 4 + 2] = v.z; bcol[q * 4 + 3] = v.w;
        }
        // stage A tile (rows r0..r0+31, dims k0..k0+31) as fp64 in LDS
        {
            int r  = t >> 3;
            int qg = t & 7;
            const float* ar = xb + (size_t)idx[r0 + r] * DD + k0 + qg * 4;
            float4 v = *(const float4*)ar;
            Ad[r][qg * 4 + 0] = (double)v.x;
            Ad[r][qg * 4 + 1] = (double)v.y;
            Ad[r][qg * 4 + 2] = (double)v.z;
            Ad[r][qg * 4 + 3] = (double)v.w;
        }
        __syncthreads();
#pragma unroll
        for (int dd = 0; dd < 32; ++dd) {
            double bd = (double)bcol[dd];
#pragma unroll
            for (int r = 0; r < RT; ++r)
                acc[r] = fma(Ad[r][dd], bd, acc[r]);   // A broadcast from LDS
        }
        __syncthreads();
    }

    // sigmoid in the reference's fp32 chain; stash row-tile of S in LDS
#pragma unroll
    for (int r = 0; r < RT; ++r) {
        float s32 = (float)acc[r];
        S[r][t] = 1.0f / (1.0f + expf(-s32));
    }
    __syncthreads();

    // top-16 per row: descending value, ties broken by lowest index
    if (t < RT) {
        float tv[TOPK]; int ti[TOPK];
#pragma unroll
        for (int q = 0; q < TOPK; ++q) { tv[q] = -INFINITY; ti[q] = 0; }
        for (int cc = 0; cc < BINSZ; ++cc) {
            float v = S[t][cc];
            if (v > tv[TOPK - 1]) {          // strict >: equal keeps earlier idx
                tv[TOPK - 1] = v; ti[TOPK - 1] = cc;
#pragma unroll
                for (int q = TOPK - 1; q > 0; --q) {
                    if (tv[q] > tv[q - 1]) { // strict >: stable among equals
                        float fv = tv[q]; tv[q] = tv[q - 1]; tv[q - 1] = fv;
                        int   fi = ti[q]; ti[q] = ti[q - 1]; ti[q - 1] = fi;
                    }
                }
            }
        }
        const int gsrc = idx[r0 + t];
        float* orow = out + ((size_t)b * NN + gsrc) * NN;
#pragma unroll
        for (int q = 0; q < TOPK; ++q)
            orow[idx[ti[q]]] = tv[q];        // all (src,dst) unique -> plain store
    }
}

// ---------------------------------------------------------------------------
extern "C" void kernel_launch(void* const* d_in, const int* in_sizes, int n_in,
                              void* d_out, int out_size, void* d_ws, size_t ws_size,
                              hipStream_t stream) {
    const float* x  = (const float*)d_in[0];
    const float* cb = (const float*)d_in[1];
    float* out      = (float*)d_out;

    int* bin_idx = (int*)d_ws;           // NPTS ints
    int* order   = bin_idx + NPTS;       // NPTS ints  (needs 128 KB of ws)

    // zero the dense (2, 8192, 8192) fp32 output (harness poisons it to 0xAA)
    hipMemsetAsync(d_out, 0, (size_t)out_size * sizeof(float), stream);

    k_bins<<<NPTS / 64, 64, 0, stream>>>(x, cb, bin_idx);
    k_sort<<<BB, 256, 0, stream>>>(bin_idx, order);
    k_sim<<<BB * NBINS * 8, 256, 0, stream>>>(x, order, out);
}